// Round 1
// baseline (273.431 us; speedup 1.0000x reference)
//
#include <hip/hip_runtime.h>

#define NN 10000
#define NE 80000
#define NB 2
#define NT 12
#define NF 64
#define ROWS (NB*NN*NT)        // 240000
#define NODE_ROWS (NB*NT)      // 24

// ---------------- K1: msg = relu(x @ W_pool^T + b_pool) ----------------
__global__ __launch_bounds__(256) void k_msg(const float* __restrict__ x,
        const float* __restrict__ Wp, const float* __restrict__ bp,
        float* __restrict__ msg) {
    __shared__ float WT[64][65];              // WT[f][g] = Wp[g*64+f], padded
    __shared__ float bs[64];
    __shared__ __align__(16) float xs[4][64];
    int tid = threadIdx.x;
    for (int i = tid; i < 4096; i += 256) {
        int g = i >> 6, f = i & 63;
        WT[f][g] = Wp[i];                     // coalesced read, conflict-free store (pad)
    }
    if (tid < 64) bs[tid] = bp[tid];
    __syncthreads();
    int wave = tid >> 6, g = tid & 63;
    for (int base = blockIdx.x * 4; base < ROWS; base += gridDim.x * 4) {
        int row = base + wave;                // ROWS % 4 == 0 -> always valid
        __syncthreads();
        xs[wave][g] = x[row * 64 + g];
        __syncthreads();
        float acc = bs[g];
        #pragma unroll
        for (int f0 = 0; f0 < 64; f0 += 4) {
            float4 xv = *(const float4*)&xs[wave][f0];   // broadcast b128
            acc += xv.x * WT[f0  ][g];
            acc += xv.y * WT[f0+1][g];
            acc += xv.z * WT[f0+2][g];
            acc += xv.w * WT[f0+3][g];
        }
        msg[row * 64 + g] = fmaxf(acc, 0.f);
    }
}

// ---------------- K2a: in-degree count ----------------
__global__ void k_count(const int* __restrict__ dst, int* __restrict__ cnt) {
    int e = blockIdx.x * blockDim.x + threadIdx.x;
    if (e < NE) atomicAdd(&cnt[dst[e]], 1);
}

// ---------------- K2b: exclusive scan -> rowptr, wofs ----------------
__global__ __launch_bounds__(1024) void k_scan(const int* __restrict__ cnt,
        int* __restrict__ rowptr, int* __restrict__ wofs) {
    __shared__ int s[1024];
    int tid = threadIdx.x;
    const int C = 10;                         // 1024*10 >= 10000
    int base = tid * C;
    int loc[C];
    int sum = 0;
    for (int i = 0; i < C; ++i) {
        int idx = base + i;
        int v = (idx < NN) ? cnt[idx] : 0;
        loc[i] = sum;                         // thread-local exclusive prefix
        sum += v;
    }
    s[tid] = sum;
    __syncthreads();
    for (int off = 1; off < 1024; off <<= 1) {   // Hillis-Steele inclusive
        int v = (tid >= off) ? s[tid - off] : 0;
        __syncthreads();
        s[tid] += v;
        __syncthreads();
    }
    int prev = (tid == 0) ? 0 : s[tid - 1];
    for (int i = 0; i < C; ++i) {
        int idx = base + i;
        if (idx < NN) {
            int v = prev + loc[i];
            rowptr[idx] = v;
            wofs[idx]   = v;
        }
    }
    if (tid == 1023) rowptr[NN] = s[1023];    // == NE
}

// ---------------- K2c: scatter edges into CSR ----------------
__global__ void k_scatter(const int* __restrict__ src, const int* __restrict__ dst,
        int* __restrict__ wofs, int* __restrict__ csr) {
    int e = blockIdx.x * blockDim.x + threadIdx.x;
    if (e < NE) {
        int pos = atomicAdd(&wofs[dst[e]], 1);
        csr[pos] = src[e];                    // order nondet, but max is order-free
    }
}

// ---------------- K3: fused segment-max + output GEMM (block per node) ----------------
__global__ __launch_bounds__(256) void k_out(const float* __restrict__ x,
        const float* __restrict__ msg,
        const float* __restrict__ Wself, const float* __restrict__ Wneigh,
        const float* __restrict__ bias,
        const int* __restrict__ rowptr, const int* __restrict__ csr,
        float* __restrict__ out) {
    __shared__ float WT[128][65];             // rows 0..63: W_self^T, 64..127: W_neigh^T
    __shared__ __align__(16) float A[NODE_ROWS][128];  // [r][0:64]=x, [64:128]=neigh
    __shared__ float bsh[64];
    int tid = threadIdx.x;
    int n = blockIdx.x;
    for (int i = tid; i < 4096; i += 256) {
        int g = i >> 6, f = i & 63;
        WT[f][g]    = Wself[i];
        WT[64+f][g] = Wneigh[i];
    }
    if (tid < 64) bsh[tid] = bias[tid];

    int rp0 = rowptr[n], rp1 = rowptr[n + 1];
    int msgBase[6], xAddr[6], rr[6], ff[6];
    #pragma unroll
    for (int k = 0; k < 6; ++k) {
        int e = tid + 256 * k;                // 0..1535 over (r=b*12+t, f)
        int r = e >> 6, f = e & 63;
        int b = r / NT, t = r - b * NT;
        rr[k] = r; ff[k] = f;
        msgBase[k] = b * (NN * NT * NF) + t * NF + f;        // + s*NT*NF per edge
        xAddr[k]   = b * (NN * NT * NF) + n * (NT * NF) + t * NF + f;
    }
    float mx[6] = {0.f, 0.f, 0.f, 0.f, 0.f, 0.f};            // relu>=0 => init 0 OK
    for (int i = rp0; i < rp1; ++i) {
        int so = csr[i] * (NT * NF);
        #pragma unroll
        for (int k = 0; k < 6; ++k)
            mx[k] = fmaxf(mx[k], msg[msgBase[k] + so]);      // coalesced
    }
    #pragma unroll
    for (int k = 0; k < 6; ++k) {
        A[rr[k]][64 + ff[k]] = mx[k];
        A[rr[k]][ff[k]]      = x[xAddr[k]];
    }
    __syncthreads();

    int g = tid & 63, rg = tid >> 6;          // 4 row-groups of 6 rows
    float acc[6];
    #pragma unroll
    for (int j = 0; j < 6; ++j) acc[j] = bsh[g];
    #pragma unroll 4
    for (int f0 = 0; f0 < 128; f0 += 4) {
        float w0 = WT[f0][g], w1 = WT[f0+1][g], w2 = WT[f0+2][g], w3 = WT[f0+3][g];
        #pragma unroll
        for (int j = 0; j < 6; ++j) {
            float4 av = *(const float4*)&A[rg * 6 + j][f0];  // broadcast b128
            acc[j] += av.x * w0 + av.y * w1 + av.z * w2 + av.w * w3;
        }
    }
    #pragma unroll
    for (int j = 0; j < 6; ++j) {
        int r = rg * 6 + j;
        int b = r / NT, t = r - b * NT;
        out[b * (NN * NT * NF) + n * (NT * NF) + t * NF + g] = acc[j];
    }
}

extern "C" void kernel_launch(void* const* d_in, const int* in_sizes, int n_in,
                              void* d_out, int out_size, void* d_ws, size_t ws_size,
                              hipStream_t stream) {
    const float* x    = (const float*)d_in[0];
    const int*   src  = (const int*)  d_in[1];
    const int*   dst  = (const int*)  d_in[2];
    const float* Wp   = (const float*)d_in[3];
    const float* bp   = (const float*)d_in[4];
    const float* Wn   = (const float*)d_in[5];
    const float* Wsf  = (const float*)d_in[6];
    const float* bias = (const float*)d_in[7];
    float* out = (float*)d_out;

    char* ws = (char*)d_ws;
    int*   cnt    = (int*)  (ws);             // NN ints
    int*   rowptr = (int*)  (ws + 40064);     // NN+1 ints
    int*   wofs   = (int*)  (ws + 80128);     // NN ints
    int*   csr    = (int*)  (ws + 120192);    // NE ints
    float* msg    = (float*)(ws + 440320);    // ROWS*NF f32 = 61.44 MB

    hipMemsetAsync(cnt, 0, NN * sizeof(int), stream);
    k_msg    <<<2048, 256, 0, stream>>>(x, Wp, bp, msg);
    k_count  <<<(NE + 255) / 256, 256, 0, stream>>>(dst, cnt);
    k_scan   <<<1, 1024, 0, stream>>>(cnt, rowptr, wofs);
    k_scatter<<<(NE + 255) / 256, 256, 0, stream>>>(src, dst, wofs, csr);
    k_out    <<<NN, 256, 0, stream>>>(x, msg, Wsf, Wn, bias, rowptr, csr, out);
}

// Round 3
// 105.402 us; speedup vs baseline: 2.5942x; 2.5942x over previous
//
#include <hip/hip_runtime.h>

#define NN 10000
#define NE 80000
#define NB 2
#define NT 12
#define NF 64
#define ROWS (NB*NN*NT)        // 240000

typedef __attribute__((ext_vector_type(8))) short bf16x8;
typedef __attribute__((ext_vector_type(4))) float f32x4;

__device__ __forceinline__ unsigned short f2b(float f) {   // f32 -> bf16 RNE
    unsigned int u = __builtin_bit_cast(unsigned int, f);
    u += 0x7fffu + ((u >> 16) & 1u);
    return (unsigned short)(u >> 16);
}
__device__ __forceinline__ float b2f_lo(unsigned int u){ return __builtin_bit_cast(float, u << 16); }
__device__ __forceinline__ float b2f_hi(unsigned int u){ return __builtin_bit_cast(float, u & 0xffff0000u); }

// ---------------- K0: weights -> bf16 (+ column permutation for W_neigh) ----------
// msg is stored with column permutation p(c) = (c&15)*4 + (c>>4) (to coalesce MFMA
// C-writes). W_cat[o][64 + p(g)] = W_neigh[o][g] absorbs it; W_cat[o][f<64] = W_self.
__global__ __launch_bounds__(256) void k_prep(const float* __restrict__ Wp,
        const float* __restrict__ Wn, const float* __restrict__ Ws,
        unsigned short* __restrict__ Wp_b, unsigned short* __restrict__ Wcat) {
    int t = threadIdx.x;
    for (int i = t; i < 4096; i += 256) {
        Wp_b[i] = f2b(Wp[i]);
        int o = i >> 6, g = i & 63;
        Wcat[o*128 + g] = f2b(Ws[i]);
        Wcat[o*128 + 64 + ((g & 15)*4 + (g >> 4))] = f2b(Wn[i]);
    }
}

// ---------------- K1: msg = relu(x @ Wp^T + bp) via MFMA; also emits xb=bf16(x) ----
__global__ __launch_bounds__(256) void k_msg(const float* __restrict__ x,
        const unsigned short* __restrict__ Wp_b, const float* __restrict__ bp,
        unsigned short* __restrict__ msg, unsigned short* __restrict__ xb) {
    __shared__ __align__(16) unsigned short A[128*72];   // [row][K=64 pad 72]
    __shared__ __align__(16) unsigned short W[64*72];    // [o]  [K=64 pad 72]
    int tid = threadIdx.x;
    {   // stage weights (bf16, row-major [o][f]) with +8 pad: 64*64 = 4096 shorts
        int row = tid >> 2, c = (tid & 3) * 16;
        bf16x8 w0 = *(const bf16x8*)(Wp_b + row*64 + c);
        bf16x8 w1 = *(const bf16x8*)(Wp_b + row*64 + c + 8);
        *(bf16x8*)(W + row*72 + c)     = w0;
        *(bf16x8*)(W + row*72 + c + 8) = w1;
    }
    int m0 = blockIdx.x * 128;
    // stage x tile: f32 -> bf16 -> LDS, and write xb to global
    #pragma unroll
    for (int k = 0; k < 8; ++k) {
        int c = tid + 256*k;                   // 0..2047 float4-chunks
        int row = c >> 4, f0 = (c & 15) * 4;
        float4 v = *(const float4*)(x + (size_t)(m0 + row)*64 + f0);
        uint2 p;
        p.x = f2b(v.x) | ((unsigned int)f2b(v.y) << 16);
        p.y = f2b(v.z) | ((unsigned int)f2b(v.w) << 16);
        *(uint2*)(A + row*72 + f0) = p;
        *(uint2*)(xb + (size_t)(m0 + row)*64 + f0) = p;
    }
    __syncthreads();

    int lane = tid & 63, w = tid >> 6;
    int cl = lane & 15, gq = lane >> 4;
    f32x4 acc[2][4] = {};
    #pragma unroll
    for (int kk = 0; kk < 2; ++kk) {
        int ko = kk*32 + gq*8;
        bf16x8 a0 = *(const bf16x8*)(A + (w*32 + cl)*72 + ko);
        bf16x8 a1 = *(const bf16x8*)(A + (w*32 + 16 + cl)*72 + ko);
        #pragma unroll
        for (int nf = 0; nf < 4; ++nf) {
            bf16x8 b = *(const bf16x8*)(W + (nf*16 + cl)*72 + ko);
            acc[0][nf] = __builtin_amdgcn_mfma_f32_16x16x32_bf16(a0, b, acc[0][nf], 0,0,0);
            acc[1][nf] = __builtin_amdgcn_mfma_f32_16x16x32_bf16(a1, b, acc[1][nf], 0,0,0);
        }
    }
    float bpv[4];
    #pragma unroll
    for (int nf = 0; nf < 4; ++nf) bpv[nf] = bp[nf*16 + cl];
    #pragma unroll
    for (int m = 0; m < 2; ++m)
    #pragma unroll
    for (int r = 0; r < 4; ++r) {
        int row = m0 + w*32 + m*16 + gq*4 + r;   // D row = 4*(lane>>4)+reg (m89)
        float v0 = fmaxf(acc[m][0][r] + bpv[0], 0.f);
        float v1 = fmaxf(acc[m][1][r] + bpv[1], 0.f);
        float v2 = fmaxf(acc[m][2][r] + bpv[2], 0.f);
        float v3 = fmaxf(acc[m][3][r] + bpv[3], 0.f);
        uint2 p;
        p.x = f2b(v0) | ((unsigned int)f2b(v1) << 16);
        p.y = f2b(v2) | ((unsigned int)f2b(v3) << 16);
        *(uint2*)(msg + (size_t)row*64 + cl*4) = p;   // permuted cols: coalesced
    }
}

// ---------------- K2: CSR build (count -> scan -> scatter) ----------------
__global__ void k_count(const int* __restrict__ dst, int* __restrict__ cnt) {
    int e = blockIdx.x * blockDim.x + threadIdx.x;
    if (e < NE) atomicAdd(&cnt[dst[e]], 1);
}

__global__ __launch_bounds__(1024) void k_scan(const int* __restrict__ cnt,
        int* __restrict__ rowptr, int* __restrict__ wofs) {
    __shared__ int s[1024];
    int tid = threadIdx.x;
    const int C = 10;
    int base = tid * C;
    int loc[C];
    int sum = 0;
    for (int i = 0; i < C; ++i) {
        int idx = base + i;
        int v = (idx < NN) ? cnt[idx] : 0;
        loc[i] = sum;
        sum += v;
    }
    s[tid] = sum;
    __syncthreads();
    for (int off = 1; off < 1024; off <<= 1) {
        int v = (tid >= off) ? s[tid - off] : 0;
        __syncthreads();
        s[tid] += v;
        __syncthreads();
    }
    int prev = (tid == 0) ? 0 : s[tid - 1];
    for (int i = 0; i < C; ++i) {
        int idx = base + i;
        if (idx < NN) {
            int v = prev + loc[i];
            rowptr[idx] = v;
            wofs[idx]   = v;
        }
    }
    if (tid == 1023) rowptr[NN] = s[1023];
}

__global__ void k_scatter(const int* __restrict__ src, const int* __restrict__ dst,
        int* __restrict__ wofs, int* __restrict__ csr) {
    int e = blockIdx.x * blockDim.x + threadIdx.x;
    if (e < NE) {
        int pos = atomicAdd(&wofs[dst[e]], 1);
        csr[pos] = src[e];
    }
}

// ---------------- K3: per-node fused segment-max + MFMA GEMM ----------------
__global__ __launch_bounds__(256) void k_out(const unsigned short* __restrict__ xb,
        const unsigned short* __restrict__ msg, const unsigned short* __restrict__ Wcat,
        const float* __restrict__ bias,
        const int* __restrict__ rowptr, const int* __restrict__ csr,
        float* __restrict__ out) {
    __shared__ __align__(16) unsigned short A[32*136];   // [24 rows pad 32][K=128 pad 136]
    __shared__ __align__(16) unsigned short W[64*136];
    int tid = threadIdx.x;
    int n = blockIdx.x;

    #pragma unroll
    for (int k = 0; k < 4; ++k) {                        // stage W_cat: 64x128 = 8192 shorts
        int c = tid + 256*k;                             // 1024 chunks of 8 bf16 (FIXED: was 512, half-staged)
        int row = c >> 4, f0 = (c & 15) * 8;
        *(bf16x8*)(W + row*136 + f0) = *(const bf16x8*)(Wcat + row*128 + f0);
    }
    {   // stage xb rows (24 x 64): 384 uint2-chunks
        int c = tid, row = c >> 4, f0 = (c & 15) * 4;
        int b = row / 12, tt = row - b*12;
        *(uint2*)(A + row*136 + f0) =
            *(const uint2*)(xb + ((size_t)(b*NN + n)*12 + tt)*64 + f0);
        if (tid < 128) {
            c = tid + 256; row = c >> 4; f0 = (c & 15)*4;
            b = row / 12; tt = row - b*12;
            *(uint2*)(A + row*136 + f0) =
                *(const uint2*)(xb + ((size_t)(b*NN + n)*12 + tt)*64 + f0);
        }
    }
    // segment-max gather: 768 dwords of (b,t,f) space, 3 per thread
    const unsigned int* msg_dw = (const unsigned int*)msg;
    int rp0 = rowptr[n], rp1 = rowptr[n + 1];
    int base[3], dsto[3];
    #pragma unroll
    for (int k = 0; k < 3; ++k) {
        int i = tid + 256*k;                 // 0..767
        int b = i / 384, rem = i - b*384;
        int tt = rem >> 5, f2 = rem & 31;
        base[k] = b * (NN*384) + rem;
        dsto[k] = (b*12 + tt)*136 + 64 + f2*2;
    }
    float mlo[3] = {0.f,0.f,0.f}, mhi[3] = {0.f,0.f,0.f};
    int e = rp0;
    for (; e + 1 < rp1; e += 2) {            // 2-unrolled: 6 loads in flight
        int s0 = csr[e] * 384, s1 = csr[e+1] * 384;
        #pragma unroll
        for (int k = 0; k < 3; ++k) {
            unsigned int u0 = msg_dw[base[k] + s0];
            unsigned int u1 = msg_dw[base[k] + s1];
            mlo[k] = fmaxf(fmaxf(mlo[k], b2f_lo(u0)), b2f_lo(u1));
            mhi[k] = fmaxf(fmaxf(mhi[k], b2f_hi(u0)), b2f_hi(u1));
        }
    }
    if (e < rp1) {
        int s0 = csr[e] * 384;
        #pragma unroll
        for (int k = 0; k < 3; ++k) {
            unsigned int u0 = msg_dw[base[k] + s0];
            mlo[k] = fmaxf(mlo[k], b2f_lo(u0));
            mhi[k] = fmaxf(mhi[k], b2f_hi(u0));
        }
    }
    #pragma unroll
    for (int k = 0; k < 3; ++k) {            // repack (exact: maxes are bf16 values)
        unsigned int lo = __builtin_bit_cast(unsigned int, mlo[k]) >> 16;
        unsigned int hi = __builtin_bit_cast(unsigned int, mhi[k]) & 0xffff0000u;
        *(unsigned int*)(A + dsto[k]) = hi | lo;
    }
    __syncthreads();

    int lane = tid & 63, w = tid >> 6;       // wave w owns output cols 16w..16w+15
    int cl = lane & 15, gq = lane >> 4;
    f32x4 acc0 = {}, acc1 = {};
    #pragma unroll
    for (int kk = 0; kk < 4; ++kk) {
        int ko = kk*32 + gq*8;
        bf16x8 a0 = *(const bf16x8*)(A + cl*136 + ko);
        bf16x8 a1 = *(const bf16x8*)(A + (16 + cl)*136 + ko);   // rows 24..31 garbage, discarded
        bf16x8 b  = *(const bf16x8*)(W + (w*16 + cl)*136 + ko);
        acc0 = __builtin_amdgcn_mfma_f32_16x16x32_bf16(a0, b, acc0, 0,0,0);
        acc1 = __builtin_amdgcn_mfma_f32_16x16x32_bf16(a1, b, acc1, 0,0,0);
    }
    float bv = bias[w*16 + cl];
    #pragma unroll
    for (int r = 0; r < 4; ++r) {
        int row = gq*4 + r;                  // rows 0..15: always valid
        int b0 = row / 12, tt = row - b0*12;
        out[((size_t)(b0*NN + n)*12 + tt)*64 + w*16 + cl] = acc0[r] + bv;
    }
    if (gq < 2) {
        #pragma unroll
        for (int r = 0; r < 4; ++r) {
            int row = 16 + gq*4 + r;         // rows 16..23
            int b0 = row / 12, tt = row - b0*12;
            out[((size_t)(b0*NN + n)*12 + tt)*64 + w*16 + cl] = acc1[r] + bv;
        }
    }
}

extern "C" void kernel_launch(void* const* d_in, const int* in_sizes, int n_in,
                              void* d_out, int out_size, void* d_ws, size_t ws_size,
                              hipStream_t stream) {
    const float* x    = (const float*)d_in[0];
    const int*   src  = (const int*)  d_in[1];
    const int*   dst  = (const int*)  d_in[2];
    const float* Wp   = (const float*)d_in[3];
    const float* bp   = (const float*)d_in[4];
    const float* Wn   = (const float*)d_in[5];   // W_neigh
    const float* Wsf  = (const float*)d_in[6];   // W_self
    const float* bias = (const float*)d_in[7];
    float* out = (float*)d_out;

    char* ws = (char*)d_ws;
    int*            cnt    = (int*)           (ws);              // 40000 B
    int*            rowptr = (int*)           (ws + 40064);      // 40004 B
    int*            wofs   = (int*)           (ws + 80128);      // 40000 B
    int*            csr    = (int*)           (ws + 120192);     // 320000 B
    unsigned short* Wp_b   = (unsigned short*)(ws + 440320);     // 8192 B
    unsigned short* Wcat   = (unsigned short*)(ws + 448512);     // 16384 B
    unsigned short* msg    = (unsigned short*)(ws + 464896);     // 30.72 MB
    unsigned short* xb     = (unsigned short*)(ws + 31184896);   // 30.72 MB

    hipMemsetAsync(cnt, 0, NN * sizeof(int), stream);
    k_prep   <<<1, 256, 0, stream>>>(Wp, Wn, Wsf, Wp_b, Wcat);
    k_msg    <<<ROWS/128, 256, 0, stream>>>(x, Wp_b, bp, msg, xb);
    k_count  <<<(NE + 255) / 256, 256, 0, stream>>>(dst, cnt);
    k_scan   <<<1, 1024, 0, stream>>>(cnt, rowptr, wofs);
    k_scatter<<<(NE + 255) / 256, 256, 0, stream>>>(src, dst, wofs, csr);
    k_out    <<<NN, 256, 0, stream>>>(xb, msg, Wcat, bias, rowptr, csr, out);
}